// Round 7
// baseline (432.225 us; speedup 1.0000x reference)
//
#include <hip/hip_runtime.h>

typedef unsigned short ush;
typedef unsigned int uint32;
typedef __attribute__((ext_vector_type(8))) __bf16 bf16x8;
typedef __attribute__((ext_vector_type(4))) float f32x4;

#define NBLK 256
#define RB   4     // batch rows per block
#define NTHR 512
#define SENC 256
#define TDEC 512
#define HDIM 128
#define HSTR 144   // h row stride (ush): 72 dw ≡ 8 mod 32 -> replicated reads/writes 2-way (free)
#define XSTR 520   // x row stride (ush)
#define PSTR 1024  // pred row stride (ush)

#define LOG2E  1.4426950408889634f
#define LOG2E2 2.8853900817779268f

__device__ __forceinline__ float bf2f(ush u){
  uint32 v = ((uint32)u) << 16;
  return __builtin_bit_cast(float, v);
}
__device__ __forceinline__ ush f2bf(float f){            // RNE
  uint32 u = __builtin_bit_cast(uint32, f);
  u = (u + 0x7FFFu + ((u >> 16) & 1u)) >> 16;
  return (ush)u;
}
__device__ __forceinline__ float lo16f(uint32 w){ return __builtin_bit_cast(float, w << 16); }
__device__ __forceinline__ float hi16f(uint32 w){ return __builtin_bit_cast(float, w & 0xFFFF0000u); }

__device__ __forceinline__ float loadf(const void* p, int i, bool f32){
  return f32 ? ((const float*)p)[i] : bf2f(((const ush*)p)[i]);
}
// raw bf16 fragment load: bit-exact copy of harness weights for bf16 inputs
__device__ __forceinline__ bf16x8 load8bf(const void* p, int i, bool f32){
  bf16x8 r;
  if (!f32){
    uint4 u = *reinterpret_cast<const uint4*>((const ush*)p + i);
    r = __builtin_bit_cast(bf16x8, u);
  } else {
    const float* fp = (const float*)p + i;
    #pragma unroll
    for (int j = 0; j < 8; ++j) r[j] = (__bf16)fp[j];
  }
  return r;
}
__device__ __forceinline__ float sigm(float x){
  return __builtin_amdgcn_rcpf(1.0f + __builtin_amdgcn_exp2f(-x * LOG2E));
}
__device__ __forceinline__ float tnh(float x){
  return 1.0f - 2.0f * __builtin_amdgcn_rcpf(__builtin_amdgcn_exp2f(x * LOG2E2) + 1.0f);
}
__device__ __forceinline__ f32x4 mfma4(const bf16x8* af, const bf16x8* b, f32x4 c){
  f32x4 r = __builtin_amdgcn_mfma_f32_16x16x32_bf16(af[0], b[0], c, 0, 0, 0);
  r = __builtin_amdgcn_mfma_f32_16x16x32_bf16(af[1], b[1], r, 0, 0, 0);
  r = __builtin_amdgcn_mfma_f32_16x16x32_bf16(af[2], b[2], r, 0, 0, 0);
  r = __builtin_amdgcn_mfma_f32_16x16x32_bf16(af[3], b[3], r, 0, 0, 0);
  return r;
}

// 256 blocks x 4 batch rows, 8 waves/block; wave w owns hidden cols [16w,16w+16).
// A-ROW REPLICATION: A[m] = h[m>>2] -> C[4q+r][n] = gates[q][n] in every reg.
// Bias rides as the C operand of the first MFMA. Pred B-matrix is
// COLUMN-REPLICATED (B[k][n]=wfc[n&1][k]) -> pred local + one shfl_xor.
// WAVE-PRIORITY STAGGER: waves 0-3 run at s_setprio(1) (one per SIMD), so at
// each barrier release the hi wave's MFMA phase completes first and its
// activation phase overlaps the lo wave's MFMA phase -> matrix and VALU
// pipes overlap instead of serializing. Math bit-identical to round 6.
__global__ void __launch_bounds__(NTHR, 2)
lstm_kernel(const void* __restrict__ xg,  const void* __restrict__ wih,
            const void* __restrict__ whh, const void* __restrict__ bih,
            const void* __restrict__ bhh, const void* __restrict__ wfc,
            const void* __restrict__ bfc, void* __restrict__ outg)
{
  __shared__ __attribute__((aligned(16))) ush x_lds[RB * XSTR];      // [row][t*2+c]
  __shared__ __attribute__((aligned(16))) ush h_lds[2][RB * HSTR];   // [buf][row][j]
  __shared__ __attribute__((aligned(16))) ush pred_lds[RB][PSTR];    // [row][d*2+o]

  const int tid   = threadIdx.x;
  const int lane  = tid & 63;
  const int wv    = tid >> 6;
  const int n     = lane & 15;   // MFMA col index within tile (= A-row m)
  const int q     = lane >> 4;   // quad; this lane's batch row
  const int gbase = wv << 4;
  const int blk   = blockIdx.x;

  // runtime storage-dtype detection (bf16 vs f32) from w_hh bit patterns
  const uint32* wp = (const uint32*)whh;
  int cnt = 0;
  #pragma unroll
  for (int i = 0; i < 64; ++i){
    uint32 e = (wp[i] >> 7) & 0xFFu;
    cnt += (e >= 90u && e <= 140u) ? 1 : 0;
  }
  const bool isf32 = (cnt < 40);

  for (int i = tid; i < 2 * RB * HSTR; i += NTHR) h_lds[0][i] = 0;  // both bufs

  // stage this block's 4 encoder rows into LDS as bf16: [row][t*2+c]
  if (!isf32){
    if (tid < 256){
      int row = tid >> 6, c = (tid & 63) * 8;
      uint4 v = *reinterpret_cast<const uint4*>((const ush*)xg + (blk * RB + row) * (SENC * 2) + c);
      *reinterpret_cast<uint4*>(&x_lds[row * XSTR + c]) = v;
    }
  } else {
    for (int i = tid; i < RB * SENC * 2; i += NTHR){
      int row = i >> 9, c = i & 511;
      x_lds[row * XSTR + c] = f2bf(((const float*)xg)[(blk * RB + row) * (SENC * 2) + c]);
    }
  }

  // ---- loop-invariant preloads: weights RAW (bit-exact for bf16) ----
  float wih0v[4], wih1v[4];
  f32x4 biasC[4];    // broadcast bias, used as C operand of first MFMA
  bf16x8 bfr[4][4];  // [gate p][kk]: B[k][g]=Whh[g][k], k=kk*32+q*8+j, g=p*128+gbase+n
  #pragma unroll
  for (int p = 0; p < 4; ++p){
    int g = p * 128 + gbase + n;
    float b = loadf(bih, g, isf32) + loadf(bhh, g, isf32);
    biasC[p][0] = b; biasC[p][1] = b; biasC[p][2] = b; biasC[p][3] = b;
    wih0v[p] = loadf(wih, g * 2 + 0, isf32);
    wih1v[p] = loadf(wih, g * 2 + 1, isf32);
    #pragma unroll
    for (int kk = 0; kk < 4; ++kk)
      bfr[p][kk] = load8bf(whh, g * HDIM + kk * 32 + q * 8, isf32);
  }
  // pred tile B-frag, COLUMN-REPLICATED: B[k][n] = wfc[n&1][k]
  bf16x8 wfcfr[4];
  #pragma unroll
  for (int kk = 0; kk < 4; ++kk){
    #pragma unroll
    for (int j = 0; j < 8; ++j){
      int k = kk * 32 + q * 8 + j;
      wfcfr[kk][j] = __builtin_bit_cast(__bf16, f2bf(loadf(wfc, (n & 1) * HDIM + k, isf32)));
    }
  }
  f32x4 pbfcC;
  {
    float pb = loadf(bfc, n & 1, isf32);
    pbfcC[0] = pb; pbfcC[1] = pb; pbfcC[2] = pb; pbfcC[3] = pb;
  }
  // per-lane feedback weights: g += wa*pv + wb*po, pv = pred[q][n&1]
  float wav[4], wbv[4];
  #pragma unroll
  for (int p = 0; p < 4; ++p){
    wav[p] = (n & 1) ? wih1v[p] : wih0v[p];
    wbv[p] = (n & 1) ? wih0v[p] : wih1v[p];
  }

  float cc = 0.0f;                   // c-state for (row q, col gbase+n)
  const int arow  = (n >> 2) * HSTR; // replicated A-row base: A[m]=h[m>>2]
  const int hwofs = q * HSTR + gbase + n;  // this lane's h-write offset
  int cur = 0;

  // WAVE-PRIORITY STAGGER: one hi-prio wave per SIMD (waves 0-3 vs 4-7).
  // Hi waves win issue arbitration after each barrier -> their MFMA phase
  // finishes first and their VALU phase overlaps the lo waves' MFMA phase.
  if (wv < 4) __builtin_amdgcn_s_setprio(1);

  __syncthreads();

  // ---------------- encoder (+ first decode cell at s==SENC) ----------------
  #pragma unroll 1
  for (int s = 0; s <= SENC; ++s){
    int t = (s < SENC) ? s : SENC - 1;   // s==SENC: inp0 = x[:,-1,:]
    uint32 xw = *reinterpret_cast<const uint32*>(&x_lds[q * XSTR + t * 2]);
    float xa = lo16f(xw), xb = hi16f(xw);

    const ush* hb = &h_lds[cur][arow];
    bf16x8 af[4];
    #pragma unroll
    for (int kk = 0; kk < 4; ++kk)
      af[kk] = *reinterpret_cast<const bf16x8*>(hb + kk * 32 + q * 8);

    f32x4 acc0 = mfma4(af, bfr[0], biasC[0]);
    f32x4 acc1 = mfma4(af, bfr[1], biasC[1]);
    float g0 = acc0[0] + wih0v[0] * xa + wih1v[0] * xb;
    float si = sigm(g0);
    f32x4 acc2 = mfma4(af, bfr[2], biasC[2]);
    float g1 = acc1[0] + wih0v[1] * xa + wih1v[1] * xb;
    float sf = sigm(g1);
    f32x4 acc3 = mfma4(af, bfr[3], biasC[3]);
    float g2 = acc2[0] + wih0v[2] * xa + wih1v[2] * xb;
    float tg = tnh(g2);
    cc = sf * cc + si * tg;
    float th = tnh(cc);
    float g3 = acc3[0] + wih0v[3] * xa + wih1v[3] * xb;
    float so = sigm(g3);
    h_lds[cur ^ 1][hwofs] = f2bf(so * th);

    __syncthreads();
    cur ^= 1;
  }

  // ---------------- decoder: pure h-recurrence + pred feedback --------------
  #pragma unroll 1
  for (int d = 0; d < TDEC - 1; ++d){
    const ush* hb = &h_lds[cur][arow];
    bf16x8 af[4];
    #pragma unroll
    for (int kk = 0; kk < 4; ++kk)
      af[kk] = *reinterpret_cast<const bf16x8*>(hb + kk * 32 + q * 8);

    // pred_d: every lane gets pred[q][n&1] locally (column-replicated B)
    f32x4 a4 = mfma4(af, wfcfr, pbfcC);
    float pv = a4[0];
    float po = __shfl_xor(pv, 1, 64);      // partner column

    f32x4 acc0 = mfma4(af, bfr[0], biasC[0]);
    f32x4 acc1 = mfma4(af, bfr[1], biasC[1]);
    float g0 = acc0[0] + wav[0] * pv + wbv[0] * po;
    float si = sigm(g0);
    f32x4 acc2 = mfma4(af, bfr[2], biasC[2]);
    float g1 = acc1[0] + wav[1] * pv + wbv[1] * po;
    float sf = sigm(g1);
    f32x4 acc3 = mfma4(af, bfr[3], biasC[3]);
    float g2 = acc2[0] + wav[2] * pv + wbv[2] * po;
    float tg = tnh(g2);
    cc = sf * cc + si * tg;
    float th = tnh(cc);
    float g3 = acc3[0] + wav[3] * pv + wbv[3] * po;
    float so = sigm(g3);
    h_lds[cur ^ 1][hwofs] = f2bf(so * th);

    if (wv == 0 && n < 2)
      pred_lds[q][d * 2 + n] = f2bf(pv);   // n&1==n for n<2

    __syncthreads();
    cur ^= 1;
  }

  // epilogue: pred_511 from final h (h_lds[cur])
  if (wv == 0){
    const ush* hb = &h_lds[cur][arow];
    bf16x8 af[4];
    #pragma unroll
    for (int kk = 0; kk < 4; ++kk)
      af[kk] = *reinterpret_cast<const bf16x8*>(hb + kk * 32 + q * 8);
    f32x4 a4 = mfma4(af, wfcfr, pbfcC);
    if (n < 2)
      pred_lds[q][(TDEC - 1) * 2 + n] = f2bf(a4[0]);
  }
  __syncthreads();

  // bulk coalesced output write: 4 rows x 1024 ush per block
  if (!isf32){
    int row = tid >> 7, c = (tid & 127) * 8;  // 512 threads x uint4
    uint4 v = *reinterpret_cast<const uint4*>(&pred_lds[row][c]);
    *reinterpret_cast<uint4*>((ush*)outg + (blk * RB + row) * (TDEC * 2) + c) = v;
  } else {
    for (int i = tid; i < RB * TDEC * 2; i += NTHR){
      int row = i >> 10, c = i & 1023;
      ((float*)outg)[(blk * RB + row) * (TDEC * 2) + c] = bf2f(pred_lds[row][c]);
    }
  }
}

extern "C" void kernel_launch(void* const* d_in, const int* in_sizes, int n_in,
                              void* d_out, int out_size, void* d_ws, size_t ws_size,
                              hipStream_t stream) {
  lstm_kernel<<<dim3(NBLK), dim3(NTHR), 0, stream>>>(
      d_in[0], d_in[1], d_in[2], d_in[3], d_in[4], d_in[5], d_in[6], d_out);
}